// Round 9
// baseline (745.341 us; speedup 1.0000x reference)
//
#include <hip/hip_runtime.h>
#include <hip/hip_bf16.h>

#define PAD 16        // pad each CSR segment to a multiple of 16 edges
#define NBKT_MAX 512  // buckets of 512 dests (dest >> 9)

typedef __attribute__((ext_vector_type(8))) short short8;
typedef __attribute__((ext_vector_type(4))) float float4v;

__device__ __forceinline__ short8 as_s8(uint4 v) {
    union { uint4 u; short8 s; } x; x.u = v; return x.s;
}

__device__ __forceinline__ int pad_up(int v) { return (v + (PAD - 1)) & ~(PAD - 1); }

// ---------------- bucketed CSR build ----------------

__global__ __launch_bounds__(256) void hist_kernel(const int* __restrict__ col,
                                                   int* __restrict__ blockHist, int E, int nbkt) {
    __shared__ int h[NBKT_MAX];
    for (int i = threadIdx.x; i < nbkt; i += 256) h[i] = 0;
    __syncthreads();
    int chunk = (E + gridDim.x - 1) / gridDim.x;
    int lo = blockIdx.x * chunk, hi = min(lo + chunk, E);
    for (int e = lo + threadIdx.x; e < hi; e += 256) atomicAdd(&h[col[e] >> 9], 1);
    __syncthreads();
    for (int i = threadIdx.x; i < nbkt; i += 256) blockHist[i * 256 + blockIdx.x] = h[i];
}

__global__ __launch_bounds__(256) void bscan_kernel(int* __restrict__ blockHist,
                                                    int* __restrict__ bktTot, int nbkt) {
    __shared__ int a[256], b[256];
    int bkt = blockIdx.x;
    int t = threadIdx.x;
    int v = blockHist[bkt * 256 + t];
    a[t] = v;
    __syncthreads();
    int* s = a; int* d = b;
    for (int off = 1; off < 256; off <<= 1) {
        int x = s[t];
        if (t >= off) x += s[t - off];
        d[t] = x;
        __syncthreads();
        int* tmp = s; s = d; d = tmp;
    }
    blockHist[bkt * 256 + t] = s[t] - v;
    if (t == 255) bktTot[bkt] = s[t];
}

__global__ void scan_small(const int* __restrict__ in, int* __restrict__ outp, int n) {
    __shared__ int a[256], b[256];
    int t = threadIdx.x;
    int v = t < n ? in[t] : 0;
    a[t] = v;
    __syncthreads();
    int* s = a; int* d = b;
    for (int off = 1; off < 256; off <<= 1) {
        int x = s[t];
        if (t >= off) x += s[t - off];
        d[t] = x;
        __syncthreads();
        int* tmp = s; s = d; d = tmp;
    }
    if (t < n) outp[t] = s[t] - v;
}

__global__ __launch_bounds__(256) void scatter_kernel(const int* __restrict__ row,
                                                      const int* __restrict__ col,
                                                      const int* __restrict__ blockHist,
                                                      const int* __restrict__ bktOff,
                                                      int2* __restrict__ pairs, int E, int nbkt) {
    __shared__ int cur[NBKT_MAX];
    for (int i = threadIdx.x; i < nbkt; i += 256)
        cur[i] = bktOff[i] + blockHist[i * 256 + blockIdx.x];
    __syncthreads();
    int chunk = (E + gridDim.x - 1) / gridDim.x;
    int lo = blockIdx.x * chunk, hi = min(lo + chunk, E);
    for (int e = lo + threadIdx.x; e < hi; e += 256) {
        int dn = col[e];
        int p = atomicAdd(&cur[dn >> 9], 1);
        pairs[p] = make_int2(row[e], dn);
    }
}

__global__ __launch_bounds__(256) void deg_pairs_kernel(
        const int2* __restrict__ pairs, const int* __restrict__ bktOff,
        const int* __restrict__ bktTot,
        int* __restrict__ deg, float* __restrict__ dinv, float* __restrict__ dinv2,
        float* __restrict__ sdeg, int N) {
    __shared__ int cnt[512];
    int b = blockIdx.x, d0 = b << 9;
    for (int i = threadIdx.x; i < 512; i += 256) cnt[i] = 0;
    __syncthreads();
    int lo = bktOff[b], hi = lo + bktTot[b];
    for (int p = lo + threadIdx.x; p < hi; p += 256)
        atomicAdd(&cnt[pairs[p].y - d0], 1);
    __syncthreads();
    for (int i = threadIdx.x; i < 512; i += 256) {
        int d = d0 + i;
        if (d < N) {
            int c = cnt[i];
            deg[d] = c;
            float v = c > 0 ? rsqrtf((float)c) : 0.0f;
            dinv[d] = v;
            dinv2[d] = v * v;
            sdeg[d] = c > 0 ? sqrtf((float)c) : 0.0f;
        }
    }
}

__global__ void scan_phaseA(const int* __restrict__ deg, int* __restrict__ chunkSum, int N) {
    int t = threadIdx.x;
    int idx = blockIdx.x * 512 + t;
    int v = idx < N ? pad_up(deg[idx]) : 0;
    for (int o = 32; o > 0; o >>= 1) v += __shfl_down(v, o, 64);
    __shared__ int wsum[8];
    if ((t & 63) == 0) wsum[t >> 6] = v;
    __syncthreads();
    if (t == 0) {
        int s = 0;
        for (int i = 0; i < 8; ++i) s += wsum[i];
        chunkSum[blockIdx.x] = s;
    }
}

__global__ void scan_phaseC(const int* __restrict__ deg, const int* __restrict__ chunkOff,
                            int* __restrict__ rowptr, int N) {
    __shared__ int a[512], b[512];
    int t = threadIdx.x;
    int idx = blockIdx.x * 512 + t;
    int v = idx < N ? pad_up(deg[idx]) : 0;
    a[t] = v;
    __syncthreads();
    int* s = a; int* d = b;
    for (int off = 1; off < 512; off <<= 1) {
        int x = s[t];
        if (t >= off) x += s[t - off];
        d[t] = x;
        __syncthreads();
        int* tmp = s; s = d; d = tmp;
    }
    if (idx < N) rowptr[idx] = chunkOff[blockIdx.x] + s[t] - v;
    if (idx == N - 1) rowptr[N] = chunkOff[blockIdx.x] + s[t];
}

__global__ __launch_bounds__(256) void cluster_kernel(const int2* __restrict__ pairs,
                                                      const int* __restrict__ bktOff,
                                                      const int* __restrict__ bktTot,
                                                      const int* __restrict__ rowptr,
                                                      int* __restrict__ srcs, int N) {
    __shared__ int cur[512];
    int b = blockIdx.x;
    int d0 = b << 9;
    for (int i = threadIdx.x; i < 512; i += 256) {
        int d = d0 + i;
        cur[i] = (d < N) ? rowptr[d] : 0;
    }
    __syncthreads();
    int lo = bktOff[b], hi = lo + bktTot[b];
    for (int p = lo + threadIdx.x; p < hi; p += 256) {
        int2 e = pairs[p];
        int pos = atomicAdd(&cur[e.y - d0], 1);
        srcs[pos] = e.x;
    }
    __syncthreads();
    for (int i = threadIdx.x; i < 512; i += 256) {
        int d = d0 + i;
        if (d < N) {
            int p = cur[i];              // == rowptr[d] + deg[d]
            int p1 = rowptr[d + 1];
            for (; p < p1; ++p) srcs[p] = N;
        }
    }
}

// ---------------- weight conversion / g init ----------------

__global__ void wcvt_kernel(const float* __restrict__ w1, const float* __restrict__ w2,
                            const float* __restrict__ wc, __hip_bfloat16* __restrict__ wf) {
    int idx = blockIdx.x * blockDim.x + threadIdx.x;
    if (idx >= 16 * 4096) return;
    int g = idx >> 12, r = idx & 4095;
    int j = r & 7, lane = (r >> 3) & 63, u = (r >> 9) & 3, t = r >> 11;
    int k = t * 32 + (lane >> 4) * 8 + j;
    int n = u * 16 + (lane & 15);
    const float* W = (g < 11) ? (w1 + (size_t)g * 4096)
                  : (g < 15) ? (w2 + (size_t)(g - 11) * 4096) : wc;
    wf[idx] = __float2bfloat16(W[k * 64 + n]);
}

__global__ void zero_pads_kernel(__hip_bfloat16* __restrict__ gbase, size_t gstride,
                                 int nbuf, int N) {
    int i = blockIdx.x * blockDim.x + threadIdx.x;
    int b = i >> 6;
    if (b < nbuf) gbase[(size_t)b * gstride + (size_t)N * 64 + (i & 63)] = __float2bfloat16(0.0f);
}

__global__ void cvt_g_kernel(const float* __restrict__ x, const float* __restrict__ dinv,
                             __hip_bfloat16* __restrict__ g, int N) {
    int i = blockIdx.x * blockDim.x + threadIdx.x;
    if (i < N * 64) g[i] = __float2bfloat16(dinv[i >> 6] * x[i]);
}

// ---------------- propagation: pure gather hop, 2 dests in flight ----------------

#define GATHER16(ACC, SP)                                                          \
    {                                                                              \
        int s0  = (SP)[0],  s1  = (SP)[1],  s2  = (SP)[2],  s3  = (SP)[3];         \
        int s4  = (SP)[4],  s5  = (SP)[5],  s6  = (SP)[6],  s7  = (SP)[7];         \
        int s8  = (SP)[8],  s9  = (SP)[9],  s10 = (SP)[10], s11 = (SP)[11];        \
        int s12 = (SP)[12], s13 = (SP)[13], s14 = (SP)[14], s15 = (SP)[15];        \
        float v0  = __bfloat162float(g_in[(size_t)s0  * 64 + lane]);               \
        float v1  = __bfloat162float(g_in[(size_t)s1  * 64 + lane]);               \
        float v2  = __bfloat162float(g_in[(size_t)s2  * 64 + lane]);               \
        float v3  = __bfloat162float(g_in[(size_t)s3  * 64 + lane]);               \
        float v4  = __bfloat162float(g_in[(size_t)s4  * 64 + lane]);               \
        float v5  = __bfloat162float(g_in[(size_t)s5  * 64 + lane]);               \
        float v6  = __bfloat162float(g_in[(size_t)s6  * 64 + lane]);               \
        float v7  = __bfloat162float(g_in[(size_t)s7  * 64 + lane]);               \
        float v8  = __bfloat162float(g_in[(size_t)s8  * 64 + lane]);               \
        float v9  = __bfloat162float(g_in[(size_t)s9  * 64 + lane]);               \
        float v10 = __bfloat162float(g_in[(size_t)s10 * 64 + lane]);               \
        float v11 = __bfloat162float(g_in[(size_t)s11 * 64 + lane]);               \
        float v12 = __bfloat162float(g_in[(size_t)s12 * 64 + lane]);               \
        float v13 = __bfloat162float(g_in[(size_t)s13 * 64 + lane]);               \
        float v14 = __bfloat162float(g_in[(size_t)s14 * 64 + lane]);               \
        float v15 = __bfloat162float(g_in[(size_t)s15 * 64 + lane]);               \
        ACC += v0;  ACC += v1;  ACC += v2;  ACC += v3;                             \
        ACC += v4;  ACC += v5;  ACC += v6;  ACC += v7;                             \
        ACC += v8;  ACC += v9;  ACC += v10; ACC += v11;                            \
        ACC += v12; ACC += v13; ACC += v14; ACC += v15;                            \
    }

__global__ __launch_bounds__(256) void hop_kernel(
        const __hip_bfloat16* __restrict__ g_in,
        const int* __restrict__ srcs, const int* __restrict__ rowptr,
        const float* __restrict__ dinv2,
        __hip_bfloat16* __restrict__ g_out, int n) {
    const int lane = threadIdx.x & 63;
    int gw = __builtin_amdgcn_readfirstlane((blockIdx.x * blockDim.x + threadIdx.x) >> 6);
    int nw = (gridDim.x * blockDim.x) >> 6;
    for (int dA = gw; dA < n; dA += 2 * nw) {
        int dB = dA + nw;
        int pa = rowptr[dA], ea = rowptr[dA + 1];
        float aggA = 0.f, aggB = 0.f;
        if (dB < n) {
            int pb = rowptr[dB], eb = rowptr[dB + 1];
            int ca = ea - pa, cb = eb - pb, cmin = min(ca, cb);
            int i = 0;
            for (; i < cmin; i += 16) {
                const int* sa = srcs + pa + i;
                const int* sb = srcs + pb + i;
                GATHER16(aggA, sa);
                GATHER16(aggB, sb);
            }
            for (; i < ca; i += 16) { const int* sa = srcs + pa + i; GATHER16(aggA, sa); }
            for (; i < cb; i += 16) { const int* sb = srcs + pb + i; GATHER16(aggB, sb); }
            g_out[(size_t)dB * 64 + lane] = __float2bfloat16(dinv2[dB] * aggB);
        } else {
            for (int p = pa; p < ea; p += 16) { const int* sa = srcs + p; GATHER16(aggA, sa); }
        }
        g_out[(size_t)dA * 64 + lane] = __float2bfloat16(dinv2[dA] * aggA);
    }
}

// ---------------- deferred multi-GEMM (MFMA), compile-time NG ----------------
// acc = sum_g G_g @ W_g ; tv = tanh(sdeg*acc + bias)
// out16 = bf16(scale * tv), scale = dinv (layer boundary) or 1 (pre-head v)

template<int NG>
__global__ __launch_bounds__(256) void final_kernel_t(
        const __hip_bfloat16* gbase, size_t gstride,
        const __hip_bfloat16* __restrict__ wf,
        const float* __restrict__ sdeg, const float* __restrict__ bias,
        const float* __restrict__ scale,
        __hip_bfloat16* out16, int ntiles) {
    const int lane = threadIdx.x & 63;
    const int col = lane & 15, quad = lane >> 4;
    int wv = (blockIdx.x * blockDim.x + threadIdx.x) >> 6;
    int nwv = (gridDim.x * blockDim.x) >> 6;
    const uint4* wfq = (const uint4*)wf;
    for (int tile = wv; tile < ntiles; tile += nwv) {
        int base = tile * 16;
        // preload all A-fragments: 2*NG independent 16B loads in flight
        uint4 A0[NG], A1[NG];
#pragma unroll
        for (int g = 0; g < NG; ++g) {
            const uint4* ga = (const uint4*)(gbase + (size_t)g * gstride)
                              + (size_t)(base + col) * 8 + quad;
            A0[g] = ga[0];
            A1[g] = ga[4];
        }
        float4v acc0 = {0.f, 0.f, 0.f, 0.f};
        float4v acc1 = {0.f, 0.f, 0.f, 0.f};
        float4v acc2 = {0.f, 0.f, 0.f, 0.f};
        float4v acc3 = {0.f, 0.f, 0.f, 0.f};
#pragma unroll
        for (int g = 0; g < NG; ++g) {
            const uint4* wg = wfq + (size_t)g * 512 + lane;
            short8 a0 = as_s8(A0[g]);
            short8 a1 = as_s8(A1[g]);
            acc0 = __builtin_amdgcn_mfma_f32_16x16x32_bf16(a0, as_s8(wg[0 * 64]), acc0, 0, 0, 0);
            acc1 = __builtin_amdgcn_mfma_f32_16x16x32_bf16(a0, as_s8(wg[1 * 64]), acc1, 0, 0, 0);
            acc2 = __builtin_amdgcn_mfma_f32_16x16x32_bf16(a0, as_s8(wg[2 * 64]), acc2, 0, 0, 0);
            acc3 = __builtin_amdgcn_mfma_f32_16x16x32_bf16(a0, as_s8(wg[3 * 64]), acc3, 0, 0, 0);
            acc0 = __builtin_amdgcn_mfma_f32_16x16x32_bf16(a1, as_s8(wg[4 * 64]), acc0, 0, 0, 0);
            acc1 = __builtin_amdgcn_mfma_f32_16x16x32_bf16(a1, as_s8(wg[5 * 64]), acc1, 0, 0, 0);
            acc2 = __builtin_amdgcn_mfma_f32_16x16x32_bf16(a1, as_s8(wg[6 * 64]), acc2, 0, 0, 0);
            acc3 = __builtin_amdgcn_mfma_f32_16x16x32_bf16(a1, as_s8(wg[7 * 64]), acc3, 0, 0, 0);
        }
#pragma unroll
        for (int r = 0; r < 4; ++r) {
            int nd = base + quad * 4 + r;
            float sd = sdeg[nd];
            float sc = scale ? scale[nd] : 1.0f;
            float f0 = sc * tanhf(sd * acc0[r] + bias[0 * 16 + col]);
            float f1 = sc * tanhf(sd * acc1[r] + bias[1 * 16 + col]);
            float f2 = sc * tanhf(sd * acc2[r] + bias[2 * 16 + col]);
            float f3 = sc * tanhf(sd * acc3[r] + bias[3 * 16 + col]);
            out16[(size_t)nd * 64 + 0 * 16 + col] = __float2bfloat16(f0);
            out16[(size_t)nd * 64 + 1 * 16 + col] = __float2bfloat16(f1);
            out16[(size_t)nd * 64 + 2 * 16 + col] = __float2bfloat16(f2);
            out16[(size_t)nd * 64 + 3 * 16 + col] = __float2bfloat16(f3);
        }
    }
}

// ---------------- MFMA head: out = v16 @ Wc + bc ----------------

__global__ __launch_bounds__(256) void head_kernel(
        const __hip_bfloat16* __restrict__ v16, const __hip_bfloat16* __restrict__ wfc,
        const float* __restrict__ bc, float* __restrict__ out, int ntiles) {
    const int lane = threadIdx.x & 63;
    const int col = lane & 15, quad = lane >> 4;
    int wv = (blockIdx.x * blockDim.x + threadIdx.x) >> 6;
    int nwv = (gridDim.x * blockDim.x) >> 6;
    const uint4* va = (const uint4*)v16;
    const uint4* wg = (const uint4*)wfc;
    for (int tile = wv; tile < ntiles; tile += nwv) {
        int base = tile * 16;
        float4v acc0 = {0.f, 0.f, 0.f, 0.f};
        float4v acc1 = {0.f, 0.f, 0.f, 0.f};
        float4v acc2 = {0.f, 0.f, 0.f, 0.f};
        float4v acc3 = {0.f, 0.f, 0.f, 0.f};
#pragma unroll
        for (int t = 0; t < 2; ++t) {
            short8 a = as_s8(va[(size_t)(base + col) * 8 + t * 4 + quad]);
            short8 b0 = as_s8(wg[(t * 4 + 0) * 64 + lane]);
            short8 b1 = as_s8(wg[(t * 4 + 1) * 64 + lane]);
            short8 b2 = as_s8(wg[(t * 4 + 2) * 64 + lane]);
            short8 b3 = as_s8(wg[(t * 4 + 3) * 64 + lane]);
            acc0 = __builtin_amdgcn_mfma_f32_16x16x32_bf16(a, b0, acc0, 0, 0, 0);
            acc1 = __builtin_amdgcn_mfma_f32_16x16x32_bf16(a, b1, acc1, 0, 0, 0);
            acc2 = __builtin_amdgcn_mfma_f32_16x16x32_bf16(a, b2, acc2, 0, 0, 0);
            acc3 = __builtin_amdgcn_mfma_f32_16x16x32_bf16(a, b3, acc3, 0, 0, 0);
        }
#pragma unroll
        for (int r = 0; r < 4; ++r) {
            int nd = base + quad * 4 + r;
            out[(size_t)nd * 64 + 0 * 16 + col] = acc0[r] + bc[0 * 16 + col];
            out[(size_t)nd * 64 + 1 * 16 + col] = acc1[r] + bc[1 * 16 + col];
            out[(size_t)nd * 64 + 2 * 16 + col] = acc2[r] + bc[2 * 16 + col];
            out[(size_t)nd * 64 + 3 * 16 + col] = acc3[r] + bc[3 * 16 + col];
        }
    }
}

// ---------------- launch ----------------

extern "C" void kernel_launch(void* const* d_in, const int* in_sizes, int n_in,
                              void* d_out, int out_size, void* d_ws, size_t ws_size,
                              hipStream_t stream) {
    const float* x  = (const float*)d_in[0];
    const int*   ei = (const int*)d_in[1];   // [2, E] int32
    const float* w1 = (const float*)d_in[2]; // [11,64,64]
    const float* b1 = (const float*)d_in[3];
    const float* w2 = (const float*)d_in[4]; // [4,64,64]
    const float* b2 = (const float*)d_in[5];
    const float* wc = (const float*)d_in[6];
    const float* bc = (const float*)d_in[7];
    float* out = (float*)d_out;

    const int N = in_sizes[0] / 64;
    const int E = in_sizes[1] / 2;
    const int K1 = 10, K2 = 3;
    const int* row = ei;
    const int* col = ei + E;
    const int Epad = E + (PAD - 1) * N + 64;
    const int NBUF = 11;
    const int nbkt = (N + 511) >> 9;
    const size_t gstride = (((size_t)(N + 1) * 64) + 127) & ~(size_t)127;

    // workspace carve (256B aligned)
    char* base = (char*)d_ws;
    auto alloc = [&](size_t bytes) { void* p = (void*)base; base += (bytes + 255) & ~(size_t)255; return p; };
    int*   deg      = (int*)alloc((size_t)N * 4);
    int*   rowptr   = (int*)alloc((size_t)(N + 1) * 4);
    int*   chunkSum = (int*)alloc(256 * 4);
    int*   chunkOff = (int*)alloc(256 * 4);
    int*   blockHist= (int*)alloc((size_t)NBKT_MAX * 256 * 4);
    int*   bktTot   = (int*)alloc((size_t)NBKT_MAX * 4);
    int*   bktOff   = (int*)alloc((size_t)NBKT_MAX * 4);
    float* dinv     = (float*)alloc((size_t)N * 4);
    float* dinv2    = (float*)alloc((size_t)N * 4);
    float* sdeg     = (float*)alloc((size_t)N * 4);
    int*   srcs     = (int*)alloc((size_t)Epad * 4);
    __hip_bfloat16* wf    = (__hip_bfloat16*)alloc((size_t)16 * 4096 * 2);
    __hip_bfloat16* gbase = (__hip_bfloat16*)alloc((size_t)NBUF * gstride * 2);

    auto G = [&](int k) { return gbase + (size_t)k * gstride; };
    int2* pairs = (int2*)G(9);            // dead until hop 9; consumed before hops
    __hip_bfloat16* vbuf16 = G(5);        // free during layer-2 (hops use G(1..4))

    const int numChunks = (N + 511) / 512;
    const int xBlocks = (N * 64 + 255) / 256;
    const int gBlocks = 2048;
    const int ntiles = (N + 15) / 16;

    // ---- bucketed CSR build + degree ----
    hist_kernel<<<256, 256, 0, stream>>>(col, blockHist, E, nbkt);
    bscan_kernel<<<nbkt, 256, 0, stream>>>(blockHist, bktTot, nbkt);
    scan_small<<<1, 256, 0, stream>>>(bktTot, bktOff, nbkt);
    scatter_kernel<<<256, 256, 0, stream>>>(row, col, blockHist, bktOff, pairs, E, nbkt);
    deg_pairs_kernel<<<nbkt, 256, 0, stream>>>(pairs, bktOff, bktTot, deg, dinv, dinv2, sdeg, N);
    scan_phaseA<<<numChunks, 512, 0, stream>>>(deg, chunkSum, N);
    scan_small<<<1, 256, 0, stream>>>(chunkSum, chunkOff, numChunks);
    scan_phaseC<<<numChunks, 512, 0, stream>>>(deg, chunkOff, rowptr, N);
    cluster_kernel<<<nbkt, 256, 0, stream>>>(pairs, bktOff, bktTot, rowptr, srcs, N);

    wcvt_kernel<<<(16 * 4096 + 255) / 256, 256, 0, stream>>>(w1, w2, wc, wf);
    zero_pads_kernel<<<(NBUF * 64 + 255) / 256, 256, 0, stream>>>(gbase, gstride, NBUF, N);
    cvt_g_kernel<<<xBlocks, 256, 0, stream>>>(x, dinv, G(0), N);

    // ---- layer 1: 10 pure-gather hops: G(k-1) -> G(k) ----
    for (int k = 1; k <= K1; ++k)
        hop_kernel<<<gBlocks, 256, 0, stream>>>(G(k - 1), srcs, rowptr, dinv2, G(k), N);

    // ---- layer-1 GEMMs + tanh + next-layer g -> G(1) (tile-local overwrite: safe) ----
    final_kernel_t<11><<<gBlocks, 256, 0, stream>>>(gbase, gstride, wf, sdeg, b1, dinv,
                                                    G(1), ntiles);

    // ---- layer 2: 3 hops: G(1)->G(2)->G(3)->G(4) ----
    for (int k = 1; k <= K2; ++k)
        hop_kernel<<<gBlocks, 256, 0, stream>>>(G(k), srcs, rowptr, dinv2, G(k + 1), N);

    // ---- layer-2 GEMMs + tanh -> v16 (bf16) ----
    final_kernel_t<4><<<gBlocks, 256, 0, stream>>>(G(1), gstride, wf + (size_t)11 * 4096,
                                                   sdeg, b2, nullptr, vbuf16, ntiles);

    // ---- MFMA head: out = v16 @ wc + bc ----
    head_kernel<<<gBlocks, 256, 0, stream>>>(vbuf16, wf + (size_t)15 * 4096, bc, out, ntiles);
}